// Round 1
// baseline (289.619 us; speedup 1.0000x reference)
//
#include <hip/hip_runtime.h>
#include <math.h>

#define S_   128
#define A_   14
#define DIM  32
#define EDGE 128
#define NPAIR 196         // A*A
#define NPOS  42          // A*3
#define NTASK 238         // NPAIR + NPOS
#define RB 16
#define DB 40
#define PB 64
#define NCLS 441
#define CPB 8

// workspace layout (floats)
#define OFF_G   0
#define OFF_WCR (OFF_G + NCLS*DIM*EDGE)        // G: 441*32*128
#define OFF_WCD (OFF_WCR + NPAIR*RB*DIM)
#define OFF_WCP (OFF_WCD + NPAIR*DB*DIM)
// total floats = OFF_WCP + NPOS*PB*DIM  (~2.24M floats, ~9 MB)

// ---------------------------------------------------------------------------
// Precompute combined tables: Wc'[ij][k][o] = sum_m (Wemb[k][m]+bemb[m]) * Wlin[(ij*32+m)][o]
// (bias folded into every row: since sum of (masked) probs == mask, the masked
//  bias term m*(bemb@Wlin_block) falls out of the 3-bin gather automatically)
// ---------------------------------------------------------------------------
__global__ __launch_bounds__(512) void make_tables(
    const float* __restrict__ Wre, const float* __restrict__ bre,
    const float* __restrict__ Wde, const float* __restrict__ bde,
    const float* __restrict__ Wpe, const float* __restrict__ bpe,
    const float* __restrict__ Wrl, const float* __restrict__ Wdl,
    const float* __restrict__ Wpl, float* __restrict__ ws)
{
    int blk = blockIdx.x;
    const float *Wemb, *bemb, *Wlin;
    float* out; int nb;
    if (blk < NPAIR) {
        int ij = blk;
        Wemb = Wre; bemb = bre; Wlin = Wrl + ij*DIM*DIM;
        out = ws + OFF_WCR + ij*RB*DIM; nb = RB;
    } else if (blk < 2*NPAIR) {
        int ij = blk - NPAIR;
        Wemb = Wde; bemb = bde; Wlin = Wdl + ij*DIM*DIM;
        out = ws + OFF_WCD + ij*DB*DIM; nb = DB;
    } else {
        int ij = blk - 2*NPAIR;
        Wemb = Wpe; bemb = bpe; Wlin = Wpl + ij*DIM*DIM;
        out = ws + OFF_WCP + ij*PB*DIM; nb = PB;
    }
    for (int t = threadIdx.x; t < nb*DIM; t += 512) {
        int k = t >> 5, o = t & 31;
        float acc = 0.f;
        #pragma unroll 8
        for (int m = 0; m < DIM; ++m) {
            float wl = Wlin[m*DIM + o];
            acc = fmaf(Wemb[k*DIM + m] + bemb[m], wl, acc);
        }
        out[t] = acc;
    }
}

// ---------------------------------------------------------------------------
// G[c][j][h] = sum_i aa_emb[c][i] * z_W[i][j][h]
// ---------------------------------------------------------------------------
__global__ __launch_bounds__(EDGE) void make_G(
    const float* __restrict__ aa_emb, const float* __restrict__ zW,
    float* __restrict__ ws)
{
    int c0 = blockIdx.x * CPB;
    int h  = threadIdx.x;
    int nc = (NCLS - c0 < CPB) ? (NCLS - c0) : CPB;
    float* G = ws + OFF_G;
    for (int j = 0; j < DIM; ++j) {
        float acc[CPB];
        #pragma unroll
        for (int cc = 0; cc < CPB; ++cc) acc[cc] = 0.f;
        for (int i = 0; i < DIM; ++i) {
            float wz = zW[(i*DIM + j)*EDGE + h];
            #pragma unroll
            for (int cc = 0; cc < CPB; ++cc) {
                int cI = c0 + cc; if (cI >= NCLS) cI = NCLS - 1;
                acc[cc] = fmaf(aa_emb[cI*DIM + i], wz, acc[cc]);
            }
        }
        for (int cc = 0; cc < nc; ++cc)
            G[(size_t)(c0+cc)*DIM*EDGE + j*EDGE + h] = acc[cc];
    }
}

// ---------------------------------------------------------------------------
// 3-bin truncated gaussian softmax around window start k0-1.
// exponent = coeff*(x-off_k)^2 = -12.5*(u-k)^2 for all three tables
// (u = (x-off0)/s). Stable via max-subtraction; scaled by mask m.
// ---------------------------------------------------------------------------
__device__ __forceinline__ void probs3(float u, int k0, float m, float* pr)
{
    float f0 = u - (float)(k0 - 1);
    float f1 = f0 - 1.f, f2 = f0 - 2.f;
    float a0 = -12.5f * f0 * f0;
    float a1 = -12.5f * f1 * f1;
    float a2 = -12.5f * f2 * f2;
    float mx = fmaxf(a0, fmaxf(a1, a2));
    float e0 = __expf(a0 - mx), e1 = __expf(a1 - mx), e2 = __expf(a2 - mx);
    float inv = m / (e0 + e1 + e2);
    pr[0] = e0 * inv; pr[1] = e1 * inv; pr[2] = e2 * inv;
}

// ---------------------------------------------------------------------------
// Main: one block per (p,q). Phase1: 238 tasks -> probs in LDS.
// Phase2: 4 segs x 32 dims gather Wc' rows (coalesced 128B rows) -> final_d[32].
// Phase3: Z[h] = z_b[h] + sum_j fd[j]*G[cls][j][h].
// ---------------------------------------------------------------------------
__global__ __launch_bounds__(128) void struct_main(
    const int*   __restrict__ aat1,
    const float* __restrict__ pos_a, const float* __restrict__ mask_a,
    const float* __restrict__ pos_b, const float* __restrict__ mask_b,
    const float* __restrict__ rots,  const float* __restrict__ trans,
    const float* __restrict__ brl,   const float* __restrict__ bdl,
    const float* __restrict__ bpl,   const float* __restrict__ zb,
    const float* __restrict__ ws,    float* __restrict__ out)
{
    const int p = blockIdx.x, q = blockIdx.y;
    __shared__ float tp [NTASK][3];
    __shared__ float tpd[NPAIR][3];
    __shared__ int   tk [NTASK];
    __shared__ int   tkd[NPAIR];
    __shared__ float sacc[4][DIM];
    __shared__ float fd[DIM];
    const int t = threadIdx.x;

    // ---- Phase 1: task probabilities ----
    for (int task = t; task < NTASK; task += 128) {
        if (task < NPAIR) {
            int i = task / A_, j = task % A_;
            float ax = pos_a[(p*A_+i)*3+0], ay = pos_a[(p*A_+i)*3+1], az = pos_a[(p*A_+i)*3+2];
            float bx = pos_b[(q*A_+j)*3+0], by = pos_b[(q*A_+j)*3+1], bz = pos_b[(q*A_+j)*3+2];
            float dx = bx-ax, dy = by-ay, dz = bz-az;
            float d  = sqrtf(dx*dx + dy*dy + dz*dz);
            float m  = mask_a[p*A_+i] * mask_b[q*A_+j];
            float u  = (d - 2.625f) * 0.8f;          // same off0/s for rough & dist
            int kf = (int)rintf(u);
            int kr = min(max(kf, 1), RB-2);
            probs3(u, kr, m, tp[task]);  tk[task]  = kr;
            int kd = min(max(kf, 1), DB-2);
            probs3(u, kd, m, tpd[task]); tkd[task] = kd;
        } else {
            int idx = task - NPAIR;
            int a = idx / 3, c = idx % 3;
            float lv = 0.f;
            #pragma unroll
            for (int jr = 0; jr < 3; ++jr)
                lv = fmaf(rots[p*9 + jr*3 + c],
                          pos_b[(q*A_+a)*3 + jr] - trans[p*3 + jr], lv);
            float m = mask_b[p*A_+a] * mask_b[q*A_+a];
            const float sp = 64.f/62.f;
            float u = (lv + 32.f + 0.5f*sp) * 0.96875f;   // 1/sp = 62/64
            int kp = min(max((int)rintf(u), 1), PB-2);
            probs3(u, kp, m, tp[task]); tk[task] = kp;
        }
    }
    __syncthreads();

    // ---- Phase 2: gather-accumulate final_d ----
    const int o = t & 31, seg = t >> 5;
    const float* __restrict__ WcR = ws + OFF_WCR + o;
    const float* __restrict__ WcD = ws + OFF_WCD + o;
    const float* __restrict__ WcP = ws + OFF_WCP + o;
    float acc = 0.f;
    for (int task = seg; task < NTASK; task += 4) {
        int   k0 = tk[task];
        float p0 = tp[task][0], p1 = tp[task][1], p2 = tp[task][2];
        if (task < NPAIR) {
            const float* b = WcR + (task*RB + k0 - 1)*DIM;
            acc = fmaf(p0, b[0], acc);
            acc = fmaf(p1, b[DIM], acc);
            acc = fmaf(p2, b[2*DIM], acc);
            int   kd = tkd[task];
            float q0 = tpd[task][0], q1 = tpd[task][1], q2 = tpd[task][2];
            const float* bd = WcD + (task*DB + kd - 1)*DIM;
            acc = fmaf(q0, bd[0], acc);
            acc = fmaf(q1, bd[DIM], acc);
            acc = fmaf(q2, bd[2*DIM], acc);
        } else {
            int idx = task - NPAIR;
            const float* bp = WcP + (idx*PB + k0 - 1)*DIM;
            acc = fmaf(p0, bp[0], acc);
            acc = fmaf(p1, bp[DIM], acc);
            acc = fmaf(p2, bp[2*DIM], acc);
        }
    }
    sacc[seg][o] = acc;
    __syncthreads();
    if (t < DIM)
        fd[t] = sacc[0][t] + sacc[1][t] + sacc[2][t] + sacc[3][t]
              + brl[t] + bdl[t] + bpl[t];
    __syncthreads();

    // ---- Phase 3: Z row ----
    const int cls = aat1[p]*21 + aat1[q];
    const float* __restrict__ G = ws + OFF_G + (size_t)cls*DIM*EDGE + t;
    float z = zb[t];
    #pragma unroll 8
    for (int j = 0; j < DIM; ++j)
        z = fmaf(fd[j], G[j*EDGE], z);
    out[((size_t)p*S_ + q)*EDGE + t] = z;
}

extern "C" void kernel_launch(void* const* d_in, const int* in_sizes, int n_in,
                              void* d_out, int out_size, void* d_ws, size_t ws_size,
                              hipStream_t stream)
{
    const int*   aat1   = (const int*)  d_in[0];
    const float* pos_a  = (const float*)d_in[2];
    const float* mask_a = (const float*)d_in[3];
    const float* pos_b  = (const float*)d_in[4];
    const float* mask_b = (const float*)d_in[5];
    const float* rots   = (const float*)d_in[6];
    const float* trans  = (const float*)d_in[7];
    const float* aa_emb = (const float*)d_in[8];
    const float* Wre    = (const float*)d_in[9];
    const float* bre    = (const float*)d_in[10];
    const float* Wde    = (const float*)d_in[11];
    const float* bde    = (const float*)d_in[12];
    const float* Wpe    = (const float*)d_in[13];
    const float* bpe    = (const float*)d_in[14];
    const float* Wrl    = (const float*)d_in[15];
    const float* brl    = (const float*)d_in[16];
    const float* Wdl    = (const float*)d_in[17];
    const float* bdl    = (const float*)d_in[18];
    const float* Wpl    = (const float*)d_in[19];
    const float* bpl    = (const float*)d_in[20];
    const float* zW     = (const float*)d_in[21];
    const float* zb     = (const float*)d_in[22];
    float* ws   = (float*)d_ws;
    float* outp = (float*)d_out;

    hipLaunchKernelGGL(make_tables, dim3(2*NPAIR + NPOS), dim3(512), 0, stream,
                       Wre, bre, Wde, bde, Wpe, bpe, Wrl, Wdl, Wpl, ws);
    hipLaunchKernelGGL(make_G, dim3((NCLS + CPB - 1)/CPB), dim3(EDGE), 0, stream,
                       aa_emb, zW, ws);
    hipLaunchKernelGGL(struct_main, dim3(S_, S_), dim3(128), 0, stream,
                       aat1, pos_a, mask_a, pos_b, mask_b, rots, trans,
                       brl, bdl, bpl, zb, ws, outp);
}

// Round 2
// 155.396 us; speedup vs baseline: 1.8637x; 1.8637x over previous
//
#include <hip/hip_runtime.h>
#include <math.h>

#define S_   128
#define A_   14
#define DIM  32
#define EDGE 128
#define NPAIR 196         // A*A
#define NPOS  42          // A*3
#define NTASK 238         // NPAIR + NPOS
#define RB 16
#define DB 40
#define PB 64
#define NCLS 441

// workspace layout (floats)
#define OFF_G   0
#define OFF_WCR (OFF_G + NCLS*DIM*EDGE)        // G: 441*32*128
#define OFF_WCD (OFF_WCR + NPAIR*RB*DIM)
#define OFF_WCP (OFF_WCD + NPAIR*DB*DIM)
// total floats = OFF_WCP + NPOS*PB*DIM  (~2.24M floats, ~9 MB)

// ---------------------------------------------------------------------------
// Precompute combined tables: Wc'[ij][k][o] = sum_m (Wemb[k][m]+bemb[m]) * Wlin[(ij*32+m)][o]
// (bias folded into every row: since sum of (masked) probs == mask, the masked
//  bias term m*(bemb@Wlin_block) falls out of the 3-bin gather automatically)
// ---------------------------------------------------------------------------
__global__ __launch_bounds__(512) void make_tables(
    const float* __restrict__ Wre, const float* __restrict__ bre,
    const float* __restrict__ Wde, const float* __restrict__ bde,
    const float* __restrict__ Wpe, const float* __restrict__ bpe,
    const float* __restrict__ Wrl, const float* __restrict__ Wdl,
    const float* __restrict__ Wpl, float* __restrict__ ws)
{
    int blk = blockIdx.x;
    const float *Wemb, *bemb, *Wlin;
    float* out; int nb;
    if (blk < NPAIR) {
        int ij = blk;
        Wemb = Wre; bemb = bre; Wlin = Wrl + ij*DIM*DIM;
        out = ws + OFF_WCR + ij*RB*DIM; nb = RB;
    } else if (blk < 2*NPAIR) {
        int ij = blk - NPAIR;
        Wemb = Wde; bemb = bde; Wlin = Wdl + ij*DIM*DIM;
        out = ws + OFF_WCD + ij*DB*DIM; nb = DB;
    } else {
        int ij = blk - 2*NPAIR;
        Wemb = Wpe; bemb = bpe; Wlin = Wpl + ij*DIM*DIM;
        out = ws + OFF_WCP + ij*PB*DIM; nb = PB;
    }
    for (int t = threadIdx.x; t < nb*DIM; t += 512) {
        int k = t >> 5, o = t & 31;
        float acc = 0.f;
        #pragma unroll 8
        for (int m = 0; m < DIM; ++m) {
            float wl = Wlin[m*DIM + o];
            acc = fmaf(Wemb[k*DIM + m] + bemb[m], wl, acc);
        }
        out[t] = acc;
    }
}

// ---------------------------------------------------------------------------
// G[c][j][h] = sum_i aa_emb[c][i] * z_W[i][j][h]
// One block per class (441 blocks, 256 threads = 4 waves).
// Thread owns (jg = tid>>7, h = tid&127) and 16 j-values in registers.
// aa_emb[c][i] is block-uniform -> scalar load; zW rows are coalesced 512B.
// ---------------------------------------------------------------------------
__global__ __launch_bounds__(256) void make_G(
    const float* __restrict__ aa_emb, const float* __restrict__ zW,
    float* __restrict__ ws)
{
    const int c  = blockIdx.x;
    const int h  = threadIdx.x & (EDGE - 1);
    const int jg = threadIdx.x >> 7;          // 0..1
    float* G = ws + OFF_G + (size_t)c*DIM*EDGE;
    float acc[16];
    #pragma unroll
    for (int jj = 0; jj < 16; ++jj) acc[jj] = 0.f;
    for (int i = 0; i < DIM; ++i) {
        float a = aa_emb[c*DIM + i];
        #pragma unroll
        for (int jj = 0; jj < 16; ++jj) {
            int j = jg + jj*2;
            acc[jj] = fmaf(a, zW[(size_t)(i*DIM + j)*EDGE + h], acc[jj]);
        }
    }
    #pragma unroll
    for (int jj = 0; jj < 16; ++jj)
        G[(jg + jj*2)*EDGE + h] = acc[jj];
}

// ---------------------------------------------------------------------------
// 3-bin truncated gaussian softmax around window start k0-1.
// exponent = coeff*(x-off_k)^2 = -12.5*(u-k)^2 for all three tables
// (u = (x-off0)/s). Stable via max-subtraction; scaled by mask m.
// ---------------------------------------------------------------------------
__device__ __forceinline__ void probs3(float u, int k0, float m, float* pr)
{
    float f0 = u - (float)(k0 - 1);
    float f1 = f0 - 1.f, f2 = f0 - 2.f;
    float a0 = -12.5f * f0 * f0;
    float a1 = -12.5f * f1 * f1;
    float a2 = -12.5f * f2 * f2;
    float mx = fmaxf(a0, fmaxf(a1, a2));
    float e0 = __expf(a0 - mx), e1 = __expf(a1 - mx), e2 = __expf(a2 - mx);
    float inv = m / (e0 + e1 + e2);
    pr[0] = e0 * inv; pr[1] = e1 * inv; pr[2] = e2 * inv;
}

// ---------------------------------------------------------------------------
// Main: one block per (p,q). Phase1: 238 tasks -> probs in LDS.
// Phase2: 4 segs x 32 dims gather Wc' rows (coalesced 128B rows) -> final_d[32].
// Phase3: Z[h] = z_b[h] + sum_j fd[j]*G[cls][j][h].
// ---------------------------------------------------------------------------
__global__ __launch_bounds__(128) void struct_main(
    const int*   __restrict__ aat1,
    const float* __restrict__ pos_a, const float* __restrict__ mask_a,
    const float* __restrict__ pos_b, const float* __restrict__ mask_b,
    const float* __restrict__ rots,  const float* __restrict__ trans,
    const float* __restrict__ brl,   const float* __restrict__ bdl,
    const float* __restrict__ bpl,   const float* __restrict__ zb,
    const float* __restrict__ ws,    float* __restrict__ out)
{
    const int p = blockIdx.x, q = blockIdx.y;
    __shared__ float tp [NTASK][3];
    __shared__ float tpd[NPAIR][3];
    __shared__ int   tk [NTASK];
    __shared__ int   tkd[NPAIR];
    __shared__ float sacc[4][DIM];
    __shared__ float fd[DIM];
    const int t = threadIdx.x;

    // ---- Phase 1: task probabilities ----
    for (int task = t; task < NTASK; task += 128) {
        if (task < NPAIR) {
            int i = task / A_, j = task % A_;
            float ax = pos_a[(p*A_+i)*3+0], ay = pos_a[(p*A_+i)*3+1], az = pos_a[(p*A_+i)*3+2];
            float bx = pos_b[(q*A_+j)*3+0], by = pos_b[(q*A_+j)*3+1], bz = pos_b[(q*A_+j)*3+2];
            float dx = bx-ax, dy = by-ay, dz = bz-az;
            float d  = sqrtf(dx*dx + dy*dy + dz*dz);
            float m  = mask_a[p*A_+i] * mask_b[q*A_+j];
            float u  = (d - 2.625f) * 0.8f;          // same off0/s for rough & dist
            int kf = (int)rintf(u);
            int kr = min(max(kf, 1), RB-2);
            probs3(u, kr, m, tp[task]);  tk[task]  = kr;
            int kd = min(max(kf, 1), DB-2);
            probs3(u, kd, m, tpd[task]); tkd[task] = kd;
        } else {
            int idx = task - NPAIR;
            int a = idx / 3, c = idx % 3;
            float lv = 0.f;
            #pragma unroll
            for (int jr = 0; jr < 3; ++jr)
                lv = fmaf(rots[p*9 + jr*3 + c],
                          pos_b[(q*A_+a)*3 + jr] - trans[p*3 + jr], lv);
            float m = mask_b[p*A_+a] * mask_b[q*A_+a];
            const float sp = 64.f/62.f;
            float u = (lv + 32.f + 0.5f*sp) * 0.96875f;   // 1/sp = 62/64
            int kp = min(max((int)rintf(u), 1), PB-2);
            probs3(u, kp, m, tp[task]); tk[task] = kp;
        }
    }
    __syncthreads();

    // ---- Phase 2: gather-accumulate final_d ----
    const int o = t & 31, seg = t >> 5;
    const float* __restrict__ WcR = ws + OFF_WCR + o;
    const float* __restrict__ WcD = ws + OFF_WCD + o;
    const float* __restrict__ WcP = ws + OFF_WCP + o;
    float acc = 0.f;
    for (int task = seg; task < NTASK; task += 4) {
        int   k0 = tk[task];
        float p0 = tp[task][0], p1 = tp[task][1], p2 = tp[task][2];
        if (task < NPAIR) {
            const float* b = WcR + (task*RB + k0 - 1)*DIM;
            acc = fmaf(p0, b[0], acc);
            acc = fmaf(p1, b[DIM], acc);
            acc = fmaf(p2, b[2*DIM], acc);
            int   kd = tkd[task];
            float q0 = tpd[task][0], q1 = tpd[task][1], q2 = tpd[task][2];
            const float* bd = WcD + (task*DB + kd - 1)*DIM;
            acc = fmaf(q0, bd[0], acc);
            acc = fmaf(q1, bd[DIM], acc);
            acc = fmaf(q2, bd[2*DIM], acc);
        } else {
            int idx = task - NPAIR;
            const float* bp = WcP + (idx*PB + k0 - 1)*DIM;
            acc = fmaf(p0, bp[0], acc);
            acc = fmaf(p1, bp[DIM], acc);
            acc = fmaf(p2, bp[2*DIM], acc);
        }
    }
    sacc[seg][o] = acc;
    __syncthreads();
    if (t < DIM)
        fd[t] = sacc[0][t] + sacc[1][t] + sacc[2][t] + sacc[3][t]
              + brl[t] + bdl[t] + bpl[t];
    __syncthreads();

    // ---- Phase 3: Z row ----
    const int cls = aat1[p]*21 + aat1[q];
    const float* __restrict__ G = ws + OFF_G + (size_t)cls*DIM*EDGE + t;
    float z = zb[t];
    #pragma unroll 8
    for (int j = 0; j < DIM; ++j)
        z = fmaf(fd[j], G[j*EDGE], z);
    out[((size_t)p*S_ + q)*EDGE + t] = z;
}

extern "C" void kernel_launch(void* const* d_in, const int* in_sizes, int n_in,
                              void* d_out, int out_size, void* d_ws, size_t ws_size,
                              hipStream_t stream)
{
    const int*   aat1   = (const int*)  d_in[0];
    const float* pos_a  = (const float*)d_in[2];
    const float* mask_a = (const float*)d_in[3];
    const float* pos_b  = (const float*)d_in[4];
    const float* mask_b = (const float*)d_in[5];
    const float* rots   = (const float*)d_in[6];
    const float* trans  = (const float*)d_in[7];
    const float* aa_emb = (const float*)d_in[8];
    const float* Wre    = (const float*)d_in[9];
    const float* bre    = (const float*)d_in[10];
    const float* Wde    = (const float*)d_in[11];
    const float* bde    = (const float*)d_in[12];
    const float* Wpe    = (const float*)d_in[13];
    const float* bpe    = (const float*)d_in[14];
    const float* Wrl    = (const float*)d_in[15];
    const float* brl    = (const float*)d_in[16];
    const float* Wdl    = (const float*)d_in[17];
    const float* bdl    = (const float*)d_in[18];
    const float* Wpl    = (const float*)d_in[19];
    const float* bpl    = (const float*)d_in[20];
    const float* zW     = (const float*)d_in[21];
    const float* zb     = (const float*)d_in[22];
    float* ws   = (float*)d_ws;
    float* outp = (float*)d_out;

    hipLaunchKernelGGL(make_tables, dim3(2*NPAIR + NPOS), dim3(512), 0, stream,
                       Wre, bre, Wde, bde, Wpe, bpe, Wrl, Wdl, Wpl, ws);
    hipLaunchKernelGGL(make_G, dim3(NCLS), dim3(256), 0, stream,
                       aa_emb, zW, ws);
    hipLaunchKernelGGL(struct_main, dim3(S_, S_), dim3(128), 0, stream,
                       aat1, pos_a, mask_a, pos_b, mask_b, rots, trans,
                       brl, bdl, bpl, zb, ws, outp);
}

// Round 3
// 116.997 us; speedup vs baseline: 2.4754x; 1.3282x over previous
//
#include <hip/hip_runtime.h>
#include <hip/hip_bf16.h>
#include <math.h>

#define S_   128
#define A_   14
#define DIM  32
#define EDGE 128
#define NPAIR 196         // A*A
#define NPOS  42          // A*3
#define NTASK 238         // NPAIR + NPOS
#define RB 16
#define DB 40
#define PB 64
#define NCLS 441

// ---- workspace layout ----
// f32 region: G[441][32][128]
#define OFF_G     0
#define OFF_ARENA (NCLS*DIM*EDGE)     // 1806336 floats; bf16 arena starts here
// bf16 arena offsets (in bf16 elements)
#define AR_WCS  0                                  // [196][16][32]  WcR+WcD
#define AR_WCR  (AR_WCS + NPAIR*RB*DIM)            // [196][16][32]  WcR
#define AR_WCD  (AR_WCR + NPAIR*RB*DIM)            // [196][40][32]  WcD
#define AR_WCDH (AR_WCD + NPAIR*DB*DIM)            // [196][40][32]  WcD + WcR[15]
#define AR_WCP  (AR_WCDH + NPAIR*DB*DIM)           // [42][64][32]
// arena total = 788480 bf16 = 1.58 MB; ws total ~8.8 MB

#define MAXJOBS (NTASK + NPAIR)   // worst case: every pair task diverges

// ---------------------------------------------------------------------------
// Combined tables (bias folded into every row; since sum of masked probs == m,
// the masked emb-bias term falls out of the 3-bin gather automatically).
// Pair block ij: R[k]=(Wre_k+bre)@Wrl_ij, D[k]=(Wde_k+bde)@Wdl_ij,
//   WcS=R+D (kf<=14 path), WcR (kf==15 rough), WcD (kf==15 dist),
//   WcDH=D+R[15] (kf>=16 path; rough collapses to edge row, err ~e^-25).
// Pos block: P[k]=(Wpe_k+bpe)@Wpl_a3.
// ---------------------------------------------------------------------------
__global__ __launch_bounds__(256) void make_tables(
    const float* __restrict__ Wre, const float* __restrict__ bre,
    const float* __restrict__ Wde, const float* __restrict__ bde,
    const float* __restrict__ Wpe, const float* __restrict__ bpe,
    const float* __restrict__ Wrl, const float* __restrict__ Wdl,
    const float* __restrict__ Wpl, float* __restrict__ ws)
{
    __hip_bfloat16* AT = (__hip_bfloat16*)(ws + OFF_ARENA);
    const int blk = blockIdx.x;
    if (blk < NPAIR) {
        __shared__ float R[RB*DIM], D[DB*DIM];
        const float* Wlr = Wrl + blk*DIM*DIM;
        const float* Wld = Wdl + blk*DIM*DIM;
        for (int idx = threadIdx.x; idx < RB*DIM; idx += 256) {
            int k = idx >> 5, o = idx & 31;
            float a = 0.f;
            #pragma unroll 8
            for (int m = 0; m < DIM; ++m)
                a = fmaf(Wre[k*DIM+m] + bre[m], Wlr[m*DIM+o], a);
            R[idx] = a;
        }
        for (int idx = threadIdx.x; idx < DB*DIM; idx += 256) {
            int k = idx >> 5, o = idx & 31;
            float a = 0.f;
            #pragma unroll 8
            for (int m = 0; m < DIM; ++m)
                a = fmaf(Wde[k*DIM+m] + bde[m], Wld[m*DIM+o], a);
            D[idx] = a;
        }
        __syncthreads();
        for (int idx = threadIdx.x; idx < RB*DIM; idx += 256) {
            AT[AR_WCS + blk*RB*DIM + idx] = __float2bfloat16(R[idx] + D[idx]);
            AT[AR_WCR + blk*RB*DIM + idx] = __float2bfloat16(R[idx]);
        }
        for (int idx = threadIdx.x; idx < DB*DIM; idx += 256) {
            int o = idx & 31;
            AT[AR_WCD  + blk*DB*DIM + idx] = __float2bfloat16(D[idx]);
            AT[AR_WCDH + blk*DB*DIM + idx] = __float2bfloat16(D[idx] + R[(RB-1)*DIM + o]);
        }
    } else {
        const int a3 = blk - NPAIR;
        const float* Wlp = Wpl + a3*DIM*DIM;
        for (int idx = threadIdx.x; idx < PB*DIM; idx += 256) {
            int k = idx >> 5, o = idx & 31;
            float a = 0.f;
            #pragma unroll 8
            for (int m = 0; m < DIM; ++m)
                a = fmaf(Wpe[k*DIM+m] + bpe[m], Wlp[m*DIM+o], a);
            AT[AR_WCP + a3*PB*DIM + idx] = __float2bfloat16(a);
        }
    }
}

// ---------------------------------------------------------------------------
// G[c][j][h] = sum_i aa_emb[c][i] * z_W[i][j][h]   (f32, one block per class)
// ---------------------------------------------------------------------------
__global__ __launch_bounds__(256) void make_G(
    const float* __restrict__ aa_emb, const float* __restrict__ zW,
    float* __restrict__ ws)
{
    const int c  = blockIdx.x;
    const int h  = threadIdx.x & (EDGE - 1);
    const int jg = threadIdx.x >> 7;          // 0..1
    float* G = ws + OFF_G + (size_t)c*DIM*EDGE;
    float acc[16];
    #pragma unroll
    for (int jj = 0; jj < 16; ++jj) acc[jj] = 0.f;
    for (int i = 0; i < DIM; ++i) {
        float a = aa_emb[c*DIM + i];
        #pragma unroll
        for (int jj = 0; jj < 16; ++jj) {
            int j = jg + jj*2;
            acc[jj] = fmaf(a, zW[(size_t)(i*DIM + j)*EDGE + h], acc[jj]);
        }
    }
    #pragma unroll
    for (int jj = 0; jj < 16; ++jj)
        G[(jg + jj*2)*EDGE + h] = acc[jj];
}

// ---------------------------------------------------------------------------
// 3-bin truncated gaussian softmax around window start k0-1; scaled by mask m.
// exponent = -12.5*(u-k)^2 for all three tables (u = (x-off0)/s).
// ---------------------------------------------------------------------------
__device__ __forceinline__ void probs3(float u, int k0, float m, float* pr)
{
    float f0 = u - (float)(k0 - 1);
    float f1 = f0 - 1.f, f2 = f0 - 2.f;
    float a0 = -12.5f * f0 * f0;
    float a1 = -12.5f * f1 * f1;
    float a2 = -12.5f * f2 * f2;
    float mx = fmaxf(a0, fmaxf(a1, a2));
    float e0 = __expf(a0 - mx), e1 = __expf(a1 - mx), e2 = __expf(a2 - mx);
    float inv = m / (e0 + e1 + e2);
    pr[0] = e0 * inv; pr[1] = e1 * inv; pr[2] = e2 * inv;
}

// ---------------------------------------------------------------------------
// Main: one block (128 thr) per (p,q).
// Phase 1: per task build job {bf16-arena offset, w0,w1,w2}; rare kf==15 pair
//          tasks emit a second job, compacted deterministically via ballot.
// Phase 2: branch-free gather loop over jobs (3 bf16 rows each), 4-seg split.
// Phase 3: Z[h] = z_b[h] + sum_j fd[j]*G[cls][j][h].
// ---------------------------------------------------------------------------
__global__ __launch_bounds__(128) void struct_main(
    const int*   __restrict__ aat1,
    const float* __restrict__ pos_a, const float* __restrict__ mask_a,
    const float* __restrict__ pos_b, const float* __restrict__ mask_b,
    const float* __restrict__ rots,  const float* __restrict__ trans,
    const float* __restrict__ brl,   const float* __restrict__ bdl,
    const float* __restrict__ bpl,   const float* __restrict__ zb,
    const float* __restrict__ ws,    float* __restrict__ out)
{
    const int p = blockIdx.x, q = blockIdx.y;
    __shared__ float4 jobs[MAXJOBS];
    __shared__ int    extCnt[4];
    __shared__ int    extTot;
    __shared__ float  sacc[4][DIM];
    __shared__ float  fd[DIM];
    const int t = threadIdx.x;
    const int lane = t & 63;
    const int wid  = t >> 6;

    bool   flag[2]  = {false, false};
    int    myPos[2] = {0, 0};
    float4 extraJ[2];
    extraJ[0] = make_float4(0,0,0,0); extraJ[1] = extraJ[0];

    // ---- Phase 1: build jobs ----
    #pragma unroll
    for (int it = 0; it < 2; ++it) {
        int task = t + it*128;
        bool f = false;
        if (task < NTASK) {
            float4 J;
            if (task < NPAIR) {
                int i = task / A_, j = task % A_;
                float ax = pos_a[(p*A_+i)*3+0], ay = pos_a[(p*A_+i)*3+1], az = pos_a[(p*A_+i)*3+2];
                float bx = pos_b[(q*A_+j)*3+0], by = pos_b[(q*A_+j)*3+1], bz = pos_b[(q*A_+j)*3+2];
                float dx = bx-ax, dy = by-ay, dz = bz-az;
                float d  = sqrtf(dx*dx + dy*dy + dz*dz);
                float m  = mask_a[p*A_+i] * mask_b[q*A_+j];
                float u  = (d - 2.625f) * 0.8f;      // shared off0/s for rough & dist
                int  kf  = (int)rintf(u);
                float w[3]; int off;
                if (kf <= RB-2) {                    // common: merged rough+dist
                    int kr = max(kf, 1);
                    probs3(u, kr, m, w);
                    off = AR_WCS + (task*RB + kr-1)*DIM;
                } else if (kf == RB-1) {             // rare shell: 2 exact jobs
                    probs3(u, RB-2, m, w);
                    off = AR_WCR + (task*RB + RB-3)*DIM;   // rough rows 13..15
                    float we[3];
                    probs3(u, RB-1, m, we);
                    extraJ[it] = make_float4(
                        __int_as_float(AR_WCD + (task*DB + RB-2)*DIM),  // dist rows 14..16
                        we[0], we[1], we[2]);
                    f = true;
                } else {                             // far: dist + folded rough edge
                    int kd = min(kf, DB-2);
                    probs3(u, kd, m, w);
                    off = AR_WCDH + (task*DB + kd-1)*DIM;
                }
                J = make_float4(__int_as_float(off), w[0], w[1], w[2]);
            } else {
                int idx = task - NPAIR;
                int a = idx / 3, c = idx % 3;
                float lv = 0.f;
                #pragma unroll
                for (int jr = 0; jr < 3; ++jr)
                    lv = fmaf(rots[p*9 + jr*3 + c],
                              pos_b[(q*A_+a)*3 + jr] - trans[p*3 + jr], lv);
                float m = mask_b[p*A_+a] * mask_b[q*A_+a];
                float u = (lv + 32.f + 0.5f*(64.f/62.f)) * 0.96875f;   // 1/s = 62/64
                int kp = min(max((int)rintf(u), 1), PB-2);
                float w[3]; probs3(u, kp, m, w);
                J = make_float4(__int_as_float(AR_WCP + (idx*PB + kp-1)*DIM),
                                w[0], w[1], w[2]);
            }
            jobs[task] = J;
        }
        unsigned long long bal = __ballot(f);
        if (lane == 0) extCnt[it*2 + wid] = __popcll(bal);
        myPos[it] = __popcll(bal & ((1ull << lane) - 1ull));
        flag[it] = f;
    }
    __syncthreads();
    if (t == 0) {
        int s = NTASK;
        #pragma unroll
        for (int g = 0; g < 4; ++g) { int c = extCnt[g]; extCnt[g] = s; s += c; }
        extTot = s;
    }
    __syncthreads();
    #pragma unroll
    for (int it = 0; it < 2; ++it)
        if (flag[it]) jobs[extCnt[it*2 + wid] + myPos[it]] = extraJ[it];
    __syncthreads();

    // ---- Phase 2: gather-accumulate fd ----
    const int o = t & 31, seg = t >> 5;
    const ushort* Tb = (const ushort*)(ws + OFF_ARENA);
    const int nj = extTot;
    float acc = 0.f;
    for (int jb = seg; jb < nj; jb += 4) {
        float4 J = jobs[jb];
        const ushort* r = Tb + __float_as_int(J.x) + o;
        float v0 = __uint_as_float(((unsigned)r[0])      << 16);
        float v1 = __uint_as_float(((unsigned)r[DIM])    << 16);
        float v2 = __uint_as_float(((unsigned)r[2*DIM])  << 16);
        acc = fmaf(J.y, v0, acc);
        acc = fmaf(J.z, v1, acc);
        acc = fmaf(J.w, v2, acc);
    }
    sacc[seg][o] = acc;
    __syncthreads();
    if (t < DIM)
        fd[t] = sacc[0][t] + sacc[1][t] + sacc[2][t] + sacc[3][t]
              + brl[t] + bdl[t] + bpl[t];
    __syncthreads();

    // ---- Phase 3: Z row ----
    const int cls = aat1[p]*21 + aat1[q];
    const float* __restrict__ G = ws + OFF_G + (size_t)cls*DIM*EDGE + t;
    float z = zb[t];
    #pragma unroll 8
    for (int j = 0; j < DIM; ++j)
        z = fmaf(fd[j], G[j*EDGE], z);
    out[((size_t)p*S_ + q)*EDGE + t] = z;
}

extern "C" void kernel_launch(void* const* d_in, const int* in_sizes, int n_in,
                              void* d_out, int out_size, void* d_ws, size_t ws_size,
                              hipStream_t stream)
{
    const int*   aat1   = (const int*)  d_in[0];
    const float* pos_a  = (const float*)d_in[2];
    const float* mask_a = (const float*)d_in[3];
    const float* pos_b  = (const float*)d_in[4];
    const float* mask_b = (const float*)d_in[5];
    const float* rots   = (const float*)d_in[6];
    const float* trans  = (const float*)d_in[7];
    const float* aa_emb = (const float*)d_in[8];
    const float* Wre    = (const float*)d_in[9];
    const float* bre    = (const float*)d_in[10];
    const float* Wde    = (const float*)d_in[11];
    const float* bde    = (const float*)d_in[12];
    const float* Wpe    = (const float*)d_in[13];
    const float* bpe    = (const float*)d_in[14];
    const float* Wrl    = (const float*)d_in[15];
    const float* brl    = (const float*)d_in[16];
    const float* Wdl    = (const float*)d_in[17];
    const float* bdl    = (const float*)d_in[18];
    const float* Wpl    = (const float*)d_in[19];
    const float* bpl    = (const float*)d_in[20];
    const float* zW     = (const float*)d_in[21];
    const float* zb     = (const float*)d_in[22];
    float* ws   = (float*)d_ws;
    float* outp = (float*)d_out;

    hipLaunchKernelGGL(make_tables, dim3(NTASK), dim3(256), 0, stream,
                       Wre, bre, Wde, bde, Wpe, bpe, Wrl, Wdl, Wpl, ws);
    hipLaunchKernelGGL(make_G, dim3(NCLS), dim3(256), 0, stream,
                       aa_emb, zW, ws);
    hipLaunchKernelGGL(struct_main, dim3(S_, S_), dim3(128), 0, stream,
                       aat1, pos_a, mask_a, pos_b, mask_b, rots, trans,
                       brl, bdl, bpl, zb, ws, outp);
}